// Round 1
// baseline (43809.076 us; speedup 1.0000x reference)
//
#include <hip/hip_runtime.h>

#define NB 256
#define NT 1024

// problem dims
#define BB   64
#define TTS  2048
#define DKV  128
#define EEM  256
#define HH1  512
#define VVV  30
#define LLS  256
#define SOS_ID 1
#define SCALE_F 0.088388347648318447f  // 1/sqrt(128)

// ws float offsets
#define OFF_PM    0        // 256   slice partial max   [b*4+s]
#define OFF_PS    256      // 256   slice partial sum   [b*4+s]
#define OFF_PCTX  512      // 32768 slice partial ctx   [d*256 + b*4 + s]
#define OFF_WSE   33280    // 2048  energies for b=0
#define OFF_EMBT  35328    // 2*16384 embT double buffer [k*64+b]
#define OFF_H1    68096    // 2*32768 h1 double buffer   [k*64+b]
#define OFF_C1    133632   // 32768 c1                   [h*64+b]
#define OFF_H2R   166400   // 2*8192 h2 row-major        [b*128+d]
#define OFF_H2T   182784   // 2*8192 h2 [d*64+b]
#define OFF_C2    199168   // 8192  c2 [d*64+b]
#define OFF_BAR   207360   // barrier: cnt @ +0, gen @ +32 (uints)
#define PRED_SZ   491520   // 64*256*30

struct Params {
  const float* key; const float* value;
  const int* enc_len; const int* y;
  const float* emb;
  const float* Wih1; const float* Whh1; const float* bih1; const float* bhh1;
  const float* Wih2; const float* Whh2; const float* bih2; const float* bhh2;
  const float* obias;
  float* out; float* ws;
};

struct SMEM {
  union {
    struct {
      float ctxT[8192];                      // [d*64 + b], 32 KB, alive A0..A2
      union { float wt[8192]; float red[8192]; } u;  // staged W rows / reduction
    } a;
    struct { float wm[16]; float wS[16]; float wctx[2048]; } c;  // attention partials
  };
};

__device__ __forceinline__ float sigm(float x) { return 1.f / (1.f + __expf(-x)); }
__device__ __forceinline__ float tanh_f(float x) {
  float t = __expf(-2.f * fabsf(x));
  float r = (1.f - t) / (1.f + t);
  return x < 0.f ? -r : r;
}

// grid barrier: one atomic arrival per block, spin on generation flag.
__device__ __forceinline__ void gbar(unsigned* bar) {
  __syncthreads();
  if (threadIdx.x == 0) {
    unsigned* cnt = bar;
    unsigned* gen = bar + 32;   // separate cache line
    __threadfence();
    unsigned g = __hip_atomic_load(gen, __ATOMIC_RELAXED, __HIP_MEMORY_SCOPE_AGENT);
    if (__hip_atomic_fetch_add(cnt, 1u, __ATOMIC_ACQ_REL, __HIP_MEMORY_SCOPE_AGENT) == NB - 1) {
      __hip_atomic_store(cnt, 0u, __ATOMIC_RELAXED, __HIP_MEMORY_SCOPE_AGENT);
      __hip_atomic_store(gen, g + 1u, __ATOMIC_RELEASE, __HIP_MEMORY_SCOPE_AGENT);
    } else {
      int guard = 0;
      while (__hip_atomic_load(gen, __ATOMIC_ACQUIRE, __HIP_MEMORY_SCOPE_AGENT) == g) {
        __builtin_amdgcn_s_sleep(4);
        if (++guard > 10000000) break;   // anti-deadlock bailout
      }
    }
    __threadfence();
  }
  __syncthreads();
}

__device__ __forceinline__ void mac8x4(float acc[8][4], const float* wt, int k, float4 x4) {
  float4 wa = *(const float4*)(wt + k*8);
  float4 wb = *(const float4*)(wt + k*8 + 4);
  float wr[8] = {wa.x, wa.y, wa.z, wa.w, wb.x, wb.y, wb.z, wb.w};
  float xr[4] = {x4.x, x4.y, x4.z, x4.w};
  #pragma unroll
  for (int r = 0; r < 8; ++r)
    #pragma unroll
    for (int c = 0; c < 4; ++c)
      acc[r][c] += wr[r] * xr[c];
}

// cross-kslot reduce (lanes ^16 ^32 sum 4 kslots) then per-wave partial to LDS
__device__ __forceinline__ void gate_reduce_store(float acc[8][4], float* red, int tid) {
  #pragma unroll
  for (int r = 0; r < 8; ++r) {
    #pragma unroll
    for (int c = 0; c < 4; ++c) {
      float v = acc[r][c];
      v += __shfl_xor(v, 16);
      v += __shfl_xor(v, 32);
      acc[r][c] = v;
    }
  }
  int wv = tid >> 6, b0 = tid & 15;
  if ((tid & 63) < 16) {
    #pragma unroll
    for (int r = 0; r < 8; ++r)
      *(float4*)(red + wv*512 + r*64 + b0*4) =
        make_float4(acc[r][0], acc[r][1], acc[r][2], acc[r][3]);
  }
}

// Phase C: online-softmax attention partials for block (b = bj>>2, slice s = bj&3).
// MEAN mode (setup): p_t = 1 for all t -> partials reduce to value.mean(axis=1).
template<bool MEAN>
__device__ void phase_attn(const Params& p, const float* qrow,
                           float* pm, float* pS, float* pctx, float* wsE,
                           SMEM* sm, int bj, int tid) {
  const int lane = tid & 63, w = tid >> 6;
  const int b = bj >> 2, s = bj & 3;
  const int len = MEAN ? TTS : p.enc_len[b];
  const int sub = lane & 31, grp = lane >> 5;
  float4 q4 = make_float4(0.f, 0.f, 0.f, 0.f);
  if constexpr (!MEAN) q4 = *(const float4*)(qrow + b*DKV + sub*4);
  float m = -1e30f, S = 0.f;
  float4 ca = make_float4(0.f, 0.f, 0.f, 0.f);
  const int t0 = (4*w + s) * 32;   // 64 wave-slots x 32 t cover T=2048
  if (t0 < len) {
    const float* kb = p.key   + (size_t)b * TTS * DKV;
    const float* vb = p.value + (size_t)b * TTS * DKV;
    for (int tt = 0; tt < 32; tt += 2) {
      int t = t0 + tt + grp;     // lanes 0-31: even t, lanes 32-63: odd t
      bool valid = t < len;
      float e;
      if constexpr (!MEAN) {
        float4 k4 = *(const float4*)(kb + (size_t)t*DKV + sub*4);
        float ep = q4.x*k4.x + q4.y*k4.y + q4.z*k4.z + q4.w*k4.w;
        ep += __shfl_xor(ep, 1); ep += __shfl_xor(ep, 2); ep += __shfl_xor(ep, 4);
        ep += __shfl_xor(ep, 8); ep += __shfl_xor(ep, 16);
        e = valid ? ep * SCALE_F : -1e30f;
        if (b == 0 && valid && sub == 0) wsE[t] = e;
      } else {
        e = 0.f;  // all t valid in mean mode
      }
      float4 v4 = *(const float4*)((p.value + (size_t)b*TTS*DKV) + (size_t)t*DKV + sub*4);
      (void)0;
      float mn = fmaxf(m, e);
      float al = __expf(m - mn);
      float pr = (MEAN || valid) ? __expf(e - mn) : 0.f;
      S = S*al + pr;
      ca.x = ca.x*al + pr*v4.x; ca.y = ca.y*al + pr*v4.y;
      ca.z = ca.z*al + pr*v4.z; ca.w = ca.w*al + pr*v4.w;
      m = mn;
    }
  }
  // merge even/odd half-wave softmax states
  float mo = __shfl_xor(m, 32);
  float M2 = fmaxf(m, mo);
  float as_ = __expf(m - M2), ao = __expf(mo - M2);
  float S2 = S*as_ + __shfl_xor(S, 32)*ao;
  float cx = ca.x*as_ + __shfl_xor(ca.x, 32)*ao;
  float cy = ca.y*as_ + __shfl_xor(ca.y, 32)*ao;
  float cz = ca.z*as_ + __shfl_xor(ca.z, 32)*ao;
  float cw = ca.w*as_ + __shfl_xor(ca.w, 32)*ao;
  if (lane == 0) { sm->c.wm[w] = M2; sm->c.wS[w] = S2; }
  if (grp == 0)
    *(float4*)(sm->c.wctx + w*DKV + sub*4) = make_float4(cx, cy, cz, cw);
  __syncthreads();
  if (tid < DKV) {
    int d = tid;
    float M = -1e30f;
    #pragma unroll
    for (int ww = 0; ww < 16; ++ww) M = fmaxf(M, sm->c.wm[ww]);
    float Z = 0.f, acc2 = 0.f;
    #pragma unroll
    for (int ww = 0; ww < 16; ++ww) {
      float aw = __expf(sm->c.wm[ww] - M);
      Z += aw * sm->c.wS[ww];
      acc2 += aw * sm->c.wctx[ww*DKV + d];
    }
    pctx[d*256 + b*4 + s] = acc2;
    if (d == 0) { pm[b*4 + s] = M; pS[b*4 + s] = Z; }
  }
}

__global__ void __launch_bounds__(NT, 4) decoder_kernel(Params p) {
  const int tid = threadIdx.x;
  const int bj = blockIdx.x;
  float* ws = p.ws;
  unsigned* bar = (unsigned*)(ws + OFF_BAR);
  float* pm = ws + OFF_PM;
  float* pS = ws + OFF_PS;
  float* pctx = ws + OFF_PCTX;
  float* wsE = ws + OFF_WSE;
  float* embT0 = ws + OFF_EMBT;
  float* embT1 = ws + OFF_EMBT + EEM*BB;
  float* h1b0 = ws + OFF_H1;
  float* h1b1 = ws + OFF_H1 + HH1*BB;
  float* c1 = ws + OFF_C1;
  float* h2r0 = ws + OFF_H2R;
  float* h2r1 = ws + OFF_H2R + BB*DKV;
  float* h2t0 = ws + OFF_H2T;
  float* h2t1 = ws + OFF_H2T + DKV*BB;
  float* c2 = ws + OFF_C2;

  __shared__ SMEM sm;

  // ---------------- setup ----------------
  {
    int gid = bj*NT + tid;
    for (int idx = gid; idx < (OFF_BAR - OFF_H1); idx += NB*NT) ws[OFF_H1 + idx] = 0.f;
    for (int idx = gid; idx < EEM*BB; idx += NB*NT) {
      int k = idx >> 6, b = idx & 63;
      embT0[k*64 + b] = p.emb[SOS_ID*EEM + k];
    }
    phase_attn<true>(p, nullptr, pm, pS, pctx, wsE, &sm, bj, tid);
  }
  gbar(bar);

  for (int i = 0; i <= LLS; ++i) {
    const int cur = i & 1;
    float* h1c = cur ? h1b1 : h1b0;
    const float* h1p = cur ? h1b0 : h1b1;
    float* h2rc = cur ? h2r1 : h2r0;
    const float* h2rp = cur ? h2r0 : h2r1;
    float* h2tc = cur ? h2t1 : h2t0;
    const float* h2tp = cur ? h2t0 : h2t1;
    const float* et = cur ? embT1 : embT0;
    float* etn = cur ? embT0 : embT1;

    // ================= phase A =================
    // A0: every block combines 4 slice partials -> ctx in LDS (transposed [d][b])
    {
      int b = tid & 63, dg = tid >> 6;
      float4 m4 = *(const float4*)(pm + b*4);
      float4 s4 = *(const float4*)(pS + b*4);
      float M = fmaxf(fmaxf(m4.x, m4.y), fmaxf(m4.z, m4.w));
      float a0 = __expf(m4.x - M), a1 = __expf(m4.y - M);
      float a2 = __expf(m4.z - M), a3 = __expf(m4.w - M);
      float Z = a0*s4.x + a1*s4.y + a2*s4.z + a3*s4.w;
      float iZ = 1.f / Z;
      a0 *= iZ; a1 *= iZ; a2 *= iZ; a3 *= iZ;
      #pragma unroll
      for (int jj = 0; jj < 8; ++jj) {
        int d = dg + jj*16;
        float4 c4 = *(const float4*)(pctx + d*256 + b*4);
        sm.a.ctxT[d*64 + b] = a0*c4.x + a1*c4.y + a2*c4.z + a3*c4.w;
      }
    }
    __syncthreads();

    if (i < LLS) {
      // A1: LSTM1 for h in {2*bj, 2*bj+1}; 8 gate rows per block
      if (tid < 896) {
        int k = tid;
        #pragma unroll
        for (int r = 0; r < 8; ++r) {
          int grow = (r >> 1)*HH1 + 2*bj + (r & 1);
          float v = (k < 384) ? p.Wih1[(size_t)grow*384 + k]
                              : p.Whh1[(size_t)grow*HH1 + (k - 384)];
          sm.a.u.wt[k*8 + r] = v;
        }
      }
      __syncthreads();
      {
        const int b0 = tid & 15, ks = tid >> 4;   // 16 b-quads x 64 k-slots
        float acc[8][4];
        #pragma unroll
        for (int r = 0; r < 8; ++r) { acc[r][0]=0.f; acc[r][1]=0.f; acc[r][2]=0.f; acc[r][3]=0.f; }
        #pragma unroll
        for (int j = 0; j < 4; ++j) {             // emb segment k<256
          int k = ks*4 + j;
          float4 x4 = *(const float4*)(et + k*64 + b0*4);
          mac8x4(acc, sm.a.u.wt, k, x4);
        }
        #pragma unroll
        for (int j = 0; j < 2; ++j) {             // ctx segment
          int d = ks*2 + j;
          float4 x4 = *(const float4*)(sm.a.ctxT + d*64 + b0*4);
          mac8x4(acc, sm.a.u.wt, 256 + d, x4);
        }
        #pragma unroll
        for (int j = 0; j < 8; ++j) {             // h1 segment
          int kk = ks*8 + j;
          float4 x4 = *(const float4*)(h1p + kk*64 + b0*4);
          mac8x4(acc, sm.a.u.wt, 384 + kk, x4);
        }
        __syncthreads();    // wt reads done; red aliases wt
        gate_reduce_store(acc, sm.a.u.red, tid);
      }
      __syncthreads();
      if (tid < 512) {
        int r = tid >> 6, b = tid & 63;
        float s = 0.f;
        #pragma unroll
        for (int w2 = 0; w2 < 16; ++w2) s += sm.a.u.red[w2*512 + r*64 + b];
        int grow = (r >> 1)*HH1 + 2*bj + (r & 1);
        s += p.bih1[grow] + p.bhh1[grow];
        sm.a.u.red[r*64 + b] = s;   // location's only reader is this thread
      }
      __syncthreads();
      if (tid < 128) {
        int hh = tid >> 6, b = tid & 63;
        int h = 2*bj + hh;
        float gi = sm.a.u.red[(hh+0)*64 + b];
        float gf = sm.a.u.red[(hh+2)*64 + b];
        float gg = sm.a.u.red[(hh+4)*64 + b];
        float go = sm.a.u.red[(hh+6)*64 + b];
        float co = c1[h*64 + b];
        float cn = sigm(gf)*co + sigm(gi)*tanh_f(gg);
        float hn = sigm(go)*tanh_f(cn);
        c1[h*64 + b] = cn;
        h1c[h*64 + b] = hn;
      }
    }

    if (i >= 1) {
      // A2: logits for step i-1 (spread 8 outputs/block, 8 lanes each)
      if (tid >= 960) {
        int ln = tid - 960;
        int oi = bj*8 + (ln >> 3);
        int sub = ln & 7;
        if (oi < BB*VVV) {
          int b = oi / VVV, v = oi - b*VVV;
          float a = 0.f;
          if (sub < 4) {
            #pragma unroll 8
            for (int e0 = 0; e0 < 32; ++e0) {
              int e = sub*32 + e0;
              a += h2rp[b*DKV + e] * p.emb[v*EEM + e];
            }
          } else {
            #pragma unroll 8
            for (int e0 = 0; e0 < 32; ++e0) {
              int d = (sub - 4)*32 + e0;
              a += sm.a.ctxT[d*64 + b] * p.emb[v*EEM + 128 + d];
            }
          }
          a += __shfl_xor(a, 1); a += __shfl_xor(a, 2); a += __shfl_xor(a, 4);
          if (sub == 0) p.out[((size_t)b*LLS + (i-1))*VVV + v] = a + p.obias[v];
        }
      }
      // A3: attention plot row i-1 (8 t per block)
      if (tid >= 896 && tid < 904) {
        int t = bj*8 + (tid - 896);
        int len0 = p.enc_len[0];
        float v = 0.f;
        if (t < len0) {
          float m0 = pm[0], m1 = pm[1], m2 = pm[2], m3 = pm[3];
          float M = fmaxf(fmaxf(m0, m1), fmaxf(m2, m3));
          float Z = __expf(m0 - M)*pS[0] + __expf(m1 - M)*pS[1]
                  + __expf(m2 - M)*pS[2] + __expf(m3 - M)*pS[3];
          v = __expf(wsE[t] - M) / Z;
        }
        p.out[PRED_SZ + (size_t)(i-1)*TTS + t] = v;
      }
    }

    if (i == LLS) break;
    gbar(bar);

    // ================= phase B =================
    if (bj < 64) {
      // LSTM2 for d in {2*bj, 2*bj+1}
      if (tid < 640) {
        int k = tid;
        #pragma unroll
        for (int r = 0; r < 8; ++r) {
          int grow = (r >> 1)*DKV + 2*bj + (r & 1);
          float v = (k < 512) ? p.Wih2[(size_t)grow*HH1 + k]
                              : p.Whh2[(size_t)grow*DKV + (k - 512)];
          sm.a.u.wt[k*8 + r] = v;
        }
      }
      __syncthreads();
      {
        const int b0 = tid & 15, ks = tid >> 4;
        float acc[8][4];
        #pragma unroll
        for (int r = 0; r < 8; ++r) { acc[r][0]=0.f; acc[r][1]=0.f; acc[r][2]=0.f; acc[r][3]=0.f; }
        #pragma unroll
        for (int j = 0; j < 8; ++j) {            // h1 segment (512)
          int k = ks*8 + j;
          float4 x4 = *(const float4*)(h1c + k*64 + b0*4);
          mac8x4(acc, sm.a.u.wt, k, x4);
        }
        #pragma unroll
        for (int j = 0; j < 2; ++j) {            // h2 segment (128)
          int d = ks*2 + j;
          float4 x4 = *(const float4*)(h2tp + d*64 + b0*4);
          mac8x4(acc, sm.a.u.wt, 512 + d, x4);
        }
        __syncthreads();
        gate_reduce_store(acc, sm.a.u.red, tid);
      }
      __syncthreads();
      if (tid < 512) {
        int r = tid >> 6, b = tid & 63;
        float s = 0.f;
        #pragma unroll
        for (int w2 = 0; w2 < 16; ++w2) s += sm.a.u.red[w2*512 + r*64 + b];
        int grow = (r >> 1)*DKV + 2*bj + (r & 1);
        s += p.bih2[grow] + p.bhh2[grow];
        sm.a.u.red[r*64 + b] = s;
      }
      __syncthreads();
      if (tid < 128) {
        int hh = tid >> 6, b = tid & 63;
        int d2 = 2*bj + hh;
        float gi = sm.a.u.red[(hh+0)*64 + b];
        float gf = sm.a.u.red[(hh+2)*64 + b];
        float gg = sm.a.u.red[(hh+4)*64 + b];
        float go = sm.a.u.red[(hh+6)*64 + b];
        float co = c2[d2*64 + b];
        float cn = sigm(gf)*co + sigm(gi)*tanh_f(gg);
        float hn = sigm(go)*tanh_f(cn);
        c2[d2*64 + b] = cn;
        h2rc[b*DKV + d2] = hn;
        h2tc[d2*64 + b] = hn;
      }
    } else if (bj < 128) {
      // stage embeddings for step i+1 on otherwise idle blocks
      int sn = i + 1;
      if (sn < LLS && tid < 256) {
        int idx = (bj - 64)*256 + tid;
        int k = idx >> 6, b = idx & 63;
        int id = p.y[b*LLS + sn - 1];
        etn[k*64 + b] = p.emb[(size_t)id*EEM + k];
      }
    }
    gbar(bar);

    // ================= phase C =================
    phase_attn<false>(p, h2rc, pm, pS, pctx, wsE, &sm, bj, tid);
    gbar(bar);
  }
}

__global__ void init_bar_kernel(unsigned* bar) {
  bar[threadIdx.x] = 0u;
}

extern "C" void kernel_launch(void* const* d_in, const int* in_sizes, int n_in,
                              void* d_out, int out_size, void* d_ws, size_t ws_size,
                              hipStream_t stream) {
  Params prm;
  prm.key     = (const float*)d_in[0];
  prm.value   = (const float*)d_in[1];
  prm.enc_len = (const int*)d_in[2];
  prm.y       = (const int*)d_in[3];
  prm.emb     = (const float*)d_in[4];
  prm.Wih1    = (const float*)d_in[5];
  prm.Whh1    = (const float*)d_in[6];
  prm.bih1    = (const float*)d_in[7];
  prm.bhh1    = (const float*)d_in[8];
  prm.Wih2    = (const float*)d_in[9];
  prm.Whh2    = (const float*)d_in[10];
  prm.bih2    = (const float*)d_in[11];
  prm.bhh2    = (const float*)d_in[12];
  prm.obias   = (const float*)d_in[13];
  prm.out = (float*)d_out;
  prm.ws  = (float*)d_ws;

  unsigned* bar = (unsigned*)((float*)d_ws + OFF_BAR);
  init_bar_kernel<<<1, 64, 0, stream>>>(bar);

  void* args[] = { &prm };
  hipError_t e = hipLaunchCooperativeKernel((const void*)decoder_kernel,
                                            dim3(NB), dim3(NT), args, 0, stream);
  if (e != hipSuccess) {
    // fallback: plain launch (256 blocks x 16 waves = 1 block/CU, co-resident)
    decoder_kernel<<<dim3(NB), dim3(NT), 0, stream>>>(prm);
  }
}

// Round 2
// 25058.717 us; speedup vs baseline: 1.7483x; 1.7483x over previous
//
#include <hip/hip_runtime.h>

#define NB 256
#define NT 1024

// problem dims
#define BB   64
#define TTS  2048
#define DKV  128
#define EEM  256
#define HH1  512
#define VVV  30
#define LLS  256
#define SOS_ID 1
#define SCALE_F 0.088388347648318447f  // 1/sqrt(128)

// ws float offsets
#define OFF_PM    0        // 256   slice partial max   [b*4+s]
#define OFF_PS    256      // 256   slice partial sum   [b*4+s]
#define OFF_PCTX  512      // 32768 slice partial ctx   [d*256 + b*4 + s]
#define OFF_WSE   33280    // 2048  energies for b=0
#define OFF_EMBT  35328    // 2*16384 embT double buffer [k*64+b]
#define OFF_H1    68096    // 2*32768 h1 double buffer   [k*64+b]
#define OFF_C1    133632   // 32768 c1                   [h*64+b]
#define OFF_H2R   166400   // 2*8192 h2 row-major        [b*128+d]
#define OFF_H2T   182784   // 2*8192 h2 [d*64+b]
#define OFF_C2    199168   // 8192  c2 [d*64+b]
#define OFF_BAR   207360   // barrier block: 2048 uints (32 group lines + master + gen)
#define PRED_SZ   491520   // 64*256*30

struct Params {
  const float* key; const float* value;
  const int* enc_len; const int* y;
  const float* emb;
  const float* Wih1; const float* Whh1; const float* bih1; const float* bhh1;
  const float* Wih2; const float* Whh2; const float* bih2; const float* bhh2;
  const float* obias;
  float* out; float* ws;
};

struct SMEM {
  union {
    struct {
      float ctxT[8192];                      // [d*64 + b], 32 KB, alive A0..A2
      union { float wt[8192]; float red[8192]; } u;  // staged W rows / reduction
    } a;
    struct { float wm[16]; float wS[16]; float wctx[2048]; } c;  // attention partials
  };
};

__device__ __forceinline__ float sigm(float x) { return 1.f / (1.f + __expf(-x)); }
__device__ __forceinline__ float tanh_f(float x) {
  float t = __expf(-2.f * fabsf(x));
  float r = (1.f - t) / (1.f + t);
  return x < 0.f ? -r : r;
}

// Hierarchical grid barrier.
// Layout (uints, 128B-separated lines): gcnt[g]=base[g*32] (g<32, 8 blocks each),
// mcnt=base[1024], gen=base[1056].
// KEY: poll with RELAXED loads (acquire-per-poll emits buffer_inv each iteration,
// nuking the whole L2 while spinning — the R1 kernel's 43ms pathology). One
// release fence (L2 writeback) before arrival, one acquire fence (L2 inv) at exit.
__device__ __forceinline__ void gbar(unsigned* base) {
  __syncthreads();
  if (threadIdx.x == 0) {
    __builtin_amdgcn_fence(__ATOMIC_RELEASE, "agent");   // writeback: publish our stores
    unsigned* gen = base + 1056;
    unsigned g = __hip_atomic_load(gen, __ATOMIC_RELAXED, __HIP_MEMORY_SCOPE_AGENT);
    unsigned* gcnt = base + (blockIdx.x & 31) * 32;
    if (__hip_atomic_fetch_add(gcnt, 1u, __ATOMIC_RELAXED, __HIP_MEMORY_SCOPE_AGENT) == 7u) {
      unsigned* mcnt = base + 1024;
      if (__hip_atomic_fetch_add(mcnt, 1u, __ATOMIC_RELAXED, __HIP_MEMORY_SCOPE_AGENT) == 31u) {
        #pragma unroll
        for (int gg = 0; gg < 32; ++gg)
          __hip_atomic_store(base + gg * 32, 0u, __ATOMIC_RELAXED, __HIP_MEMORY_SCOPE_AGENT);
        __hip_atomic_store(mcnt, 0u, __ATOMIC_RELAXED, __HIP_MEMORY_SCOPE_AGENT);
        __hip_atomic_store(gen, g + 1u, __ATOMIC_RELEASE, __HIP_MEMORY_SCOPE_AGENT);
      }
    }
    int guard = 0;
    while (__hip_atomic_load(gen, __ATOMIC_RELAXED, __HIP_MEMORY_SCOPE_AGENT) == g) {
      __builtin_amdgcn_s_sleep(2);
      if (++guard > 50000000) break;   // anti-deadlock bailout
    }
    __builtin_amdgcn_fence(__ATOMIC_ACQUIRE, "agent");   // single L2 inv: see everyone's data
  }
  __syncthreads();
}

__device__ __forceinline__ void mac8x4(float acc[8][4], const float* wt, int k, float4 x4) {
  float4 wa = *(const float4*)(wt + k*8);
  float4 wb = *(const float4*)(wt + k*8 + 4);
  float wr[8] = {wa.x, wa.y, wa.z, wa.w, wb.x, wb.y, wb.z, wb.w};
  float xr[4] = {x4.x, x4.y, x4.z, x4.w};
  #pragma unroll
  for (int r = 0; r < 8; ++r)
    #pragma unroll
    for (int c = 0; c < 4; ++c)
      acc[r][c] += wr[r] * xr[c];
}

// cross-kslot reduce (lanes ^16 ^32 sum 4 kslots) then per-wave partial to LDS
__device__ __forceinline__ void gate_reduce_store(float acc[8][4], float* red, int tid) {
  #pragma unroll
  for (int r = 0; r < 8; ++r) {
    #pragma unroll
    for (int c = 0; c < 4; ++c) {
      float v = acc[r][c];
      v += __shfl_xor(v, 16);
      v += __shfl_xor(v, 32);
      acc[r][c] = v;
    }
  }
  int wv = tid >> 6, b0 = tid & 15;
  if ((tid & 63) < 16) {
    #pragma unroll
    for (int r = 0; r < 8; ++r)
      *(float4*)(red + wv*512 + r*64 + b0*4) =
        make_float4(acc[r][0], acc[r][1], acc[r][2], acc[r][3]);
  }
}

// Phase C: online-softmax attention partials for block (b = bj>>2, slice s = bj&3).
// MEAN mode (setup): p_t = 1 for all t -> partials reduce to value.mean(axis=1).
// Chunked 4 t-pairs/iter: 8 loads issue back-to-back before the softmax chain (MLP).
template<bool MEAN>
__device__ void phase_attn(const Params& p, const float* qrow,
                           float* pm, float* pS, float* pctx, float* wsE,
                           SMEM* sm, int bj, int tid) {
  const int lane = tid & 63, w = tid >> 6;
  const int b = bj >> 2, s = bj & 3;
  const int len = MEAN ? TTS : p.enc_len[b];
  const int sub = lane & 31, grp = lane >> 5;
  float4 q4 = make_float4(0.f, 0.f, 0.f, 0.f);
  if constexpr (!MEAN) q4 = *(const float4*)(qrow + b*DKV + sub*4);
  float m = -1e30f, S = 0.f;
  float4 ca = make_float4(0.f, 0.f, 0.f, 0.f);
  const int t0 = (4*w + s) * 32;   // 64 wave-slots x 32 t cover T=2048
  if (t0 < len) {
    const float* kb = p.key   + (size_t)b * TTS * DKV;
    const float* vb = p.value + (size_t)b * TTS * DKV;
    if constexpr (MEAN) {
      for (int tt = 0; tt < 32; tt += 2) {
        int t = t0 + tt + grp;
        float4 v4 = *(const float4*)(vb + (size_t)t*DKV + sub*4);
        S += 1.f;
        ca.x += v4.x; ca.y += v4.y; ca.z += v4.z; ca.w += v4.w;
      }
      m = 0.f;
    } else {
      for (int tt = 0; tt < 32; tt += 8) {   // 4 chunks x 4 t-pairs
        float e[4]; float4 v4[4]; bool val[4];
        #pragma unroll
        for (int j = 0; j < 4; ++j) {
          int t = t0 + tt + 2*j + grp;       // rows exist up to T=2048: safe load
          val[j] = t < len;
          float4 k4 = *(const float4*)(kb + (size_t)t*DKV + sub*4);
          v4[j] = *(const float4*)(vb + (size_t)t*DKV + sub*4);
          float ep = q4.x*k4.x + q4.y*k4.y + q4.z*k4.z + q4.w*k4.w;
          ep += __shfl_xor(ep, 1); ep += __shfl_xor(ep, 2); ep += __shfl_xor(ep, 4);
          ep += __shfl_xor(ep, 8); ep += __shfl_xor(ep, 16);
          e[j] = val[j] ? ep * SCALE_F : -1e30f;
          if (b == 0 && val[j] && sub == 0) wsE[t] = e[j];
        }
        float mc = fmaxf(fmaxf(e[0], e[1]), fmaxf(e[2], e[3]));
        float mn = fmaxf(m, mc);
        float al = __expf(m - mn);
        float pr[4];
        #pragma unroll
        for (int j = 0; j < 4; ++j) pr[j] = val[j] ? __expf(e[j] - mn) : 0.f;
        S = S*al + pr[0] + pr[1] + pr[2] + pr[3];
        ca.x = ca.x*al + pr[0]*v4[0].x + pr[1]*v4[1].x + pr[2]*v4[2].x + pr[3]*v4[3].x;
        ca.y = ca.y*al + pr[0]*v4[0].y + pr[1]*v4[1].y + pr[2]*v4[2].y + pr[3]*v4[3].y;
        ca.z = ca.z*al + pr[0]*v4[0].z + pr[1]*v4[1].z + pr[2]*v4[2].z + pr[3]*v4[3].z;
        ca.w = ca.w*al + pr[0]*v4[0].w + pr[1]*v4[1].w + pr[2]*v4[2].w + pr[3]*v4[3].w;
        m = mn;
      }
    }
  }
  // merge even/odd half-wave softmax states
  float mo = __shfl_xor(m, 32);
  float M2 = fmaxf(m, mo);
  float as_ = __expf(m - M2), ao = __expf(mo - M2);
  float S2 = S*as_ + __shfl_xor(S, 32)*ao;
  float cx = ca.x*as_ + __shfl_xor(ca.x, 32)*ao;
  float cy = ca.y*as_ + __shfl_xor(ca.y, 32)*ao;
  float cz = ca.z*as_ + __shfl_xor(ca.z, 32)*ao;
  float cw = ca.w*as_ + __shfl_xor(ca.w, 32)*ao;
  if (lane == 0) { sm->c.wm[w] = M2; sm->c.wS[w] = S2; }
  if (grp == 0)
    *(float4*)(sm->c.wctx + w*DKV + sub*4) = make_float4(cx, cy, cz, cw);
  __syncthreads();
  if (tid < DKV) {
    int d = tid;
    float M = -1e30f;
    #pragma unroll
    for (int ww = 0; ww < 16; ++ww) M = fmaxf(M, sm->c.wm[ww]);
    float Z = 0.f, acc2 = 0.f;
    #pragma unroll
    for (int ww = 0; ww < 16; ++ww) {
      float aw = __expf(sm->c.wm[ww] - M);
      Z += aw * sm->c.wS[ww];
      acc2 += aw * sm->c.wctx[ww*DKV + d];
    }
    pctx[d*256 + b*4 + s] = acc2;
    if (d == 0) { pm[b*4 + s] = M; pS[b*4 + s] = Z; }
  }
}

__global__ void __launch_bounds__(NT, 4) decoder_kernel(Params p) {
  const int tid = threadIdx.x;
  const int bj = blockIdx.x;
  float* ws = p.ws;
  unsigned* bar = (unsigned*)(ws + OFF_BAR);
  float* pm = ws + OFF_PM;
  float* pS = ws + OFF_PS;
  float* pctx = ws + OFF_PCTX;
  float* wsE = ws + OFF_WSE;
  float* embT0 = ws + OFF_EMBT;
  float* embT1 = ws + OFF_EMBT + EEM*BB;
  float* h1b0 = ws + OFF_H1;
  float* h1b1 = ws + OFF_H1 + HH1*BB;
  float* c1 = ws + OFF_C1;
  float* h2r0 = ws + OFF_H2R;
  float* h2r1 = ws + OFF_H2R + BB*DKV;
  float* h2t0 = ws + OFF_H2T;
  float* h2t1 = ws + OFF_H2T + DKV*BB;
  float* c2 = ws + OFF_C2;

  __shared__ SMEM sm;

  // ---------------- setup ----------------
  {
    int gid = bj*NT + tid;
    for (int idx = gid; idx < (OFF_BAR - OFF_H1); idx += NB*NT) ws[OFF_H1 + idx] = 0.f;
    for (int idx = gid; idx < EEM*BB; idx += NB*NT) {
      int k = idx >> 6, b = idx & 63;
      embT0[k*64 + b] = p.emb[SOS_ID*EEM + k];
    }
    phase_attn<true>(p, nullptr, pm, pS, pctx, wsE, &sm, bj, tid);
  }
  gbar(bar);

  for (int i = 0; i <= LLS; ++i) {
    const int cur = i & 1;
    float* h1c = cur ? h1b1 : h1b0;
    const float* h1p = cur ? h1b0 : h1b1;
    float* h2rc = cur ? h2r1 : h2r0;
    const float* h2rp = cur ? h2r0 : h2r1;
    float* h2tc = cur ? h2t1 : h2t0;
    const float* h2tp = cur ? h2t0 : h2t1;
    const float* et = cur ? embT1 : embT0;
    float* etn = cur ? embT0 : embT1;

    // ================= phase A =================
    // A0: every block combines 4 slice partials -> ctx in LDS (transposed [d][b])
    {
      int b = tid & 63, dg = tid >> 6;
      float4 m4 = *(const float4*)(pm + b*4);
      float4 s4 = *(const float4*)(pS + b*4);
      float M = fmaxf(fmaxf(m4.x, m4.y), fmaxf(m4.z, m4.w));
      float a0 = __expf(m4.x - M), a1 = __expf(m4.y - M);
      float a2 = __expf(m4.z - M), a3 = __expf(m4.w - M);
      float Z = a0*s4.x + a1*s4.y + a2*s4.z + a3*s4.w;
      float iZ = 1.f / Z;
      a0 *= iZ; a1 *= iZ; a2 *= iZ; a3 *= iZ;
      #pragma unroll
      for (int jj = 0; jj < 8; ++jj) {
        int d = dg + jj*16;
        float4 c4 = *(const float4*)(pctx + d*256 + b*4);
        sm.a.ctxT[d*64 + b] = a0*c4.x + a1*c4.y + a2*c4.z + a3*c4.w;
      }
    }
    __syncthreads();

    if (i < LLS) {
      // A1: LSTM1 for h in {2*bj, 2*bj+1}; 8 gate rows per block
      if (tid < 896) {
        int k = tid;
        #pragma unroll
        for (int r = 0; r < 8; ++r) {
          int grow = (r >> 1)*HH1 + 2*bj + (r & 1);
          float v = (k < 384) ? p.Wih1[(size_t)grow*384 + k]
                              : p.Whh1[(size_t)grow*HH1 + (k - 384)];
          sm.a.u.wt[k*8 + r] = v;
        }
      }
      __syncthreads();
      {
        const int b0 = tid & 15, ks = tid >> 4;   // 16 b-quads x 64 k-slots
        float acc[8][4];
        #pragma unroll
        for (int r = 0; r < 8; ++r) { acc[r][0]=0.f; acc[r][1]=0.f; acc[r][2]=0.f; acc[r][3]=0.f; }
        #pragma unroll
        for (int j = 0; j < 4; ++j) {             // emb segment k<256
          int k = ks*4 + j;
          float4 x4 = *(const float4*)(et + k*64 + b0*4);
          mac8x4(acc, sm.a.u.wt, k, x4);
        }
        #pragma unroll
        for (int j = 0; j < 2; ++j) {             // ctx segment
          int d = ks*2 + j;
          float4 x4 = *(const float4*)(sm.a.ctxT + d*64 + b0*4);
          mac8x4(acc, sm.a.u.wt, 256 + d, x4);
        }
        #pragma unroll
        for (int j = 0; j < 8; ++j) {             // h1 segment
          int kk = ks*8 + j;
          float4 x4 = *(const float4*)(h1p + kk*64 + b0*4);
          mac8x4(acc, sm.a.u.wt, 384 + kk, x4);
        }
        __syncthreads();    // wt reads done; red aliases wt
        gate_reduce_store(acc, sm.a.u.red, tid);
      }
      __syncthreads();
      if (tid < 512) {
        int r = tid >> 6, b = tid & 63;
        float s = 0.f;
        #pragma unroll
        for (int w2 = 0; w2 < 16; ++w2) s += sm.a.u.red[w2*512 + r*64 + b];
        int grow = (r >> 1)*HH1 + 2*bj + (r & 1);
        s += p.bih1[grow] + p.bhh1[grow];
        sm.a.u.red[r*64 + b] = s;   // location's only reader is this thread
      }
      __syncthreads();
      if (tid < 128) {
        int hh = tid >> 6, b = tid & 63;
        int h = 2*bj + hh;
        float gi = sm.a.u.red[(hh+0)*64 + b];
        float gf = sm.a.u.red[(hh+2)*64 + b];
        float gg = sm.a.u.red[(hh+4)*64 + b];
        float go = sm.a.u.red[(hh+6)*64 + b];
        float co = c1[h*64 + b];
        float cn = sigm(gf)*co + sigm(gi)*tanh_f(gg);
        float hn = sigm(go)*tanh_f(cn);
        c1[h*64 + b] = cn;
        h1c[h*64 + b] = hn;
      }
    }

    if (i >= 1) {
      // A2: logits for step i-1 (spread 8 outputs/block, 8 lanes each)
      if (tid >= 960) {
        int ln = tid - 960;
        int oi = bj*8 + (ln >> 3);
        int sub = ln & 7;
        if (oi < BB*VVV) {
          int b = oi / VVV, v = oi - b*VVV;
          float a = 0.f;
          if (sub < 4) {
            #pragma unroll 8
            for (int e0 = 0; e0 < 32; ++e0) {
              int e = sub*32 + e0;
              a += h2rp[b*DKV + e] * p.emb[v*EEM + e];
            }
          } else {
            #pragma unroll 8
            for (int e0 = 0; e0 < 32; ++e0) {
              int d = (sub - 4)*32 + e0;
              a += sm.a.ctxT[d*64 + b] * p.emb[v*EEM + 128 + d];
            }
          }
          a += __shfl_xor(a, 1); a += __shfl_xor(a, 2); a += __shfl_xor(a, 4);
          if (sub == 0) p.out[((size_t)b*LLS + (i-1))*VVV + v] = a + p.obias[v];
        }
      }
      // A3: attention plot row i-1 (8 t per block)
      if (tid >= 896 && tid < 904) {
        int t = bj*8 + (tid - 896);
        int len0 = p.enc_len[0];
        float v = 0.f;
        if (t < len0) {
          float m0 = pm[0], m1 = pm[1], m2 = pm[2], m3 = pm[3];
          float M = fmaxf(fmaxf(m0, m1), fmaxf(m2, m3));
          float Z = __expf(m0 - M)*pS[0] + __expf(m1 - M)*pS[1]
                  + __expf(m2 - M)*pS[2] + __expf(m3 - M)*pS[3];
          v = __expf(wsE[t] - M) / Z;
        }
        p.out[PRED_SZ + (size_t)(i-1)*TTS + t] = v;
      }
    }

    if (i == LLS) break;
    gbar(bar);

    // ================= phase B =================
    if (bj < 64) {
      // LSTM2 for d in {2*bj, 2*bj+1}
      if (tid < 640) {
        int k = tid;
        #pragma unroll
        for (int r = 0; r < 8; ++r) {
          int grow = (r >> 1)*DKV + 2*bj + (r & 1);
          float v = (k < 512) ? p.Wih2[(size_t)grow*HH1 + k]
                              : p.Whh2[(size_t)grow*DKV + (k - 512)];
          sm.a.u.wt[k*8 + r] = v;
        }
      }
      __syncthreads();
      {
        const int b0 = tid & 15, ks = tid >> 4;
        float acc[8][4];
        #pragma unroll
        for (int r = 0; r < 8; ++r) { acc[r][0]=0.f; acc[r][1]=0.f; acc[r][2]=0.f; acc[r][3]=0.f; }
        #pragma unroll
        for (int j = 0; j < 8; ++j) {            // h1 segment (512)
          int k = ks*8 + j;
          float4 x4 = *(const float4*)(h1c + k*64 + b0*4);
          mac8x4(acc, sm.a.u.wt, k, x4);
        }
        #pragma unroll
        for (int j = 0; j < 2; ++j) {            // h2 segment (128)
          int d = ks*2 + j;
          float4 x4 = *(const float4*)(h2tp + d*64 + b0*4);
          mac8x4(acc, sm.a.u.wt, 512 + d, x4);
        }
        __syncthreads();
        gate_reduce_store(acc, sm.a.u.red, tid);
      }
      __syncthreads();
      if (tid < 512) {
        int r = tid >> 6, b = tid & 63;
        float s = 0.f;
        #pragma unroll
        for (int w2 = 0; w2 < 16; ++w2) s += sm.a.u.red[w2*512 + r*64 + b];
        int grow = (r >> 1)*DKV + 2*bj + (r & 1);
        s += p.bih2[grow] + p.bhh2[grow];
        sm.a.u.red[r*64 + b] = s;
      }
      __syncthreads();
      if (tid < 128) {
        int hh = tid >> 6, b = tid & 63;
        int d2 = 2*bj + hh;
        float gi = sm.a.u.red[(hh+0)*64 + b];
        float gf = sm.a.u.red[(hh+2)*64 + b];
        float gg = sm.a.u.red[(hh+4)*64 + b];
        float go = sm.a.u.red[(hh+6)*64 + b];
        float co = c2[d2*64 + b];
        float cn = sigm(gf)*co + sigm(gi)*tanh_f(gg);
        float hn = sigm(go)*tanh_f(cn);
        c2[d2*64 + b] = cn;
        h2rc[b*DKV + d2] = hn;
        h2tc[d2*64 + b] = hn;
      }
    } else if (bj < 128) {
      // stage embeddings for step i+1 on otherwise idle blocks
      int sn = i + 1;
      if (sn < LLS && tid < 256) {
        int idx = (bj - 64)*256 + tid;
        int k = idx >> 6, b = idx & 63;
        int id = p.y[b*LLS + sn - 1];
        etn[k*64 + b] = p.emb[(size_t)id*EEM + k];
      }
    }
    gbar(bar);

    // ================= phase C =================
    phase_attn<false>(p, h2rc, pm, pS, pctx, wsE, &sm, bj, tid);
    gbar(bar);
  }
}

__global__ void init_bar_kernel(unsigned* bar) {
  int i = blockIdx.x * blockDim.x + threadIdx.x;
  if (i < 2048) bar[i] = 0u;
}

extern "C" void kernel_launch(void* const* d_in, const int* in_sizes, int n_in,
                              void* d_out, int out_size, void* d_ws, size_t ws_size,
                              hipStream_t stream) {
  Params prm;
  prm.key     = (const float*)d_in[0];
  prm.value   = (const float*)d_in[1];
  prm.enc_len = (const int*)d_in[2];
  prm.y       = (const int*)d_in[3];
  prm.emb     = (const float*)d_in[4];
  prm.Wih1    = (const float*)d_in[5];
  prm.Whh1    = (const float*)d_in[6];
  prm.bih1    = (const float*)d_in[7];
  prm.bhh1    = (const float*)d_in[8];
  prm.Wih2    = (const float*)d_in[9];
  prm.Whh2    = (const float*)d_in[10];
  prm.bih2    = (const float*)d_in[11];
  prm.bhh2    = (const float*)d_in[12];
  prm.obias   = (const float*)d_in[13];
  prm.out = (float*)d_out;
  prm.ws  = (float*)d_ws;

  unsigned* bar = (unsigned*)((float*)d_ws + OFF_BAR);
  init_bar_kernel<<<8, 256, 0, stream>>>(bar);

  void* args[] = { &prm };
  hipError_t e = hipLaunchCooperativeKernel((const void*)decoder_kernel,
                                            dim3(NB), dim3(NT), args, 0, stream);
  if (e != hipSuccess) {
    // fallback: plain launch (256 blocks x 16 waves = 1 block/CU, co-resident)
    decoder_kernel<<<dim3(NB), dim3(NT), 0, stream>>>(prm);
  }
}

// Round 3
// 21057.243 us; speedup vs baseline: 2.0805x; 1.1900x over previous
//
#include <hip/hip_runtime.h>

#define NB 256
#define NT 1024

// problem dims
#define BB   64
#define TTS  2048
#define DKV  128
#define EEM  256
#define HH1  512
#define VVV  30
#define LLS  256
#define SOS_ID 1
#define SCALE_F 0.088388347648318447f  // 1/sqrt(128)

// ws float offsets
#define OFF_PM    0        // 256   slice partial max   [b*4+s]
#define OFF_PS    256      // 256   slice partial sum   [b*4+s]
#define OFF_PCTX  512      // 32768 slice partial ctx   [d*256 + b*4 + s]
#define OFF_WSE   33280    // 2048  energies for b=0
#define OFF_EMBT  35328    // 2*16384 embT double buffer [k*64+b]
#define OFF_H1    68096    // 2*32768 h1 double buffer   [k*64+b]
#define OFF_C1    133632   // 32768 c1                   [h*64+b]
#define OFF_H2R   166400   // 2*8192 h2 row-major        [b*128+d]
#define OFF_H2T   182784   // 2*8192 h2 [d*64+b]
#define OFF_C2    199168   // 8192  c2 [d*64+b]
#define OFF_BAR   207360   // barrier block: 2048 uints
#define OFF_KBF   212992   // bf16 K, 16777216 ushorts (8388608 float slots)
#define OFF_VBF   8601600  // bf16 V, 16777216 ushorts
#define WS_NEED_BYTES 67960832ull
#define PRED_SZ   491520   // 64*256*30

struct Params {
  const float* key; const float* value;
  const int* enc_len; const int* y;
  const float* emb;
  const float* Wih1; const float* Whh1; const float* bih1; const float* bhh1;
  const float* Wih2; const float* Whh2; const float* bih2; const float* bhh2;
  const float* obias;
  float* out; float* ws;
};

struct SMEM {
  union {
    struct {
      float ctxT[8192];                      // [d*64 + b], 32 KB
      union { float wt[8192]; float red[8192]; } u;  // weights (from regs) / reduction
    } a;
    struct { float wm[16]; float wS[16]; float wctx[2048]; } c;  // attention partials
  };
};

__device__ __forceinline__ float sigm(float x) { return 1.f / (1.f + __expf(-x)); }
__device__ __forceinline__ float tanh_f(float x) {
  float t = __expf(-2.f * fabsf(x));
  float r = (1.f - t) / (1.f + t);
  return x < 0.f ? -r : r;
}
__device__ __forceinline__ unsigned bfr(float f) {  // fp32 -> bf16 bits, RNE
  unsigned u = __float_as_uint(f);
  return (u + 0x7FFFu + ((u >> 16) & 1u)) >> 16;
}
__device__ __forceinline__ float b2f(unsigned short h) {
  return __uint_as_float(((unsigned)h) << 16);
}

// Hierarchical grid barrier. Relaxed polls (acquire-per-poll = L2 inv per
// iteration = R1's 43ms pathology); one release fence before arrival, one
// acquire fence at exit.
__device__ __forceinline__ void gbar(unsigned* base) {
  __syncthreads();
  if (threadIdx.x == 0) {
    __builtin_amdgcn_fence(__ATOMIC_RELEASE, "agent");
    unsigned* gen = base + 1056;
    unsigned g = __hip_atomic_load(gen, __ATOMIC_RELAXED, __HIP_MEMORY_SCOPE_AGENT);
    unsigned* gcnt = base + (blockIdx.x & 31) * 32;
    if (__hip_atomic_fetch_add(gcnt, 1u, __ATOMIC_RELAXED, __HIP_MEMORY_SCOPE_AGENT) == 7u) {
      unsigned* mcnt = base + 1024;
      if (__hip_atomic_fetch_add(mcnt, 1u, __ATOMIC_RELAXED, __HIP_MEMORY_SCOPE_AGENT) == 31u) {
        #pragma unroll
        for (int gg = 0; gg < 32; ++gg)
          __hip_atomic_store(base + gg * 32, 0u, __ATOMIC_RELAXED, __HIP_MEMORY_SCOPE_AGENT);
        __hip_atomic_store(mcnt, 0u, __ATOMIC_RELAXED, __HIP_MEMORY_SCOPE_AGENT);
        __hip_atomic_store(gen, g + 1u, __ATOMIC_RELEASE, __HIP_MEMORY_SCOPE_AGENT);
      }
    }
    int guard = 0;
    while (__hip_atomic_load(gen, __ATOMIC_RELAXED, __HIP_MEMORY_SCOPE_AGENT) == g) {
      __builtin_amdgcn_s_sleep(2);
      if (++guard > 50000000) break;
    }
    __builtin_amdgcn_fence(__ATOMIC_ACQUIRE, "agent");
  }
  __syncthreads();
}

__device__ __forceinline__ void mac8x4(float acc[8][4], const float* wt, int k, float4 x4) {
  float4 wa = *(const float4*)(wt + k*8);
  float4 wb = *(const float4*)(wt + k*8 + 4);
  float wr[8] = {wa.x, wa.y, wa.z, wa.w, wb.x, wb.y, wb.z, wb.w};
  float xr[4] = {x4.x, x4.y, x4.z, x4.w};
  #pragma unroll
  for (int r = 0; r < 8; ++r)
    #pragma unroll
    for (int c = 0; c < 4; ++c)
      acc[r][c] += wr[r] * xr[c];
}

// cross-kslot reduce then per-wave partial to LDS
__device__ __forceinline__ void gate_reduce_store(float acc[8][4], float* red, int tid) {
  #pragma unroll
  for (int r = 0; r < 8; ++r) {
    #pragma unroll
    for (int c = 0; c < 4; ++c) {
      float v = acc[r][c];
      v += __shfl_xor(v, 16);
      v += __shfl_xor(v, 32);
      acc[r][c] = v;
    }
  }
  int wv = tid >> 6, b0 = tid & 15;
  if ((tid & 63) < 16) {
    #pragma unroll
    for (int r = 0; r < 8; ++r)
      *(float4*)(red + wv*512 + r*64 + b0*4) =
        make_float4(acc[r][0], acc[r][1], acc[r][2], acc[r][3]);
  }
}

// Phase C: online-softmax attention partials for block (b = bj>>2, s = bj&3).
// Row order rotated per (b,w) to decorrelate the 64 concurrent 1MB-strided streams.
template<bool MEAN, bool BF16>
__device__ void phase_attn(const Params& p, const float* qrow,
                           const unsigned short* kbf, const unsigned short* vbf,
                           float* pm, float* pS, float* pctx, float* wsE,
                           SMEM* sm, int bj, int tid) {
  const int lane = tid & 63, w = tid >> 6;
  const int b = bj >> 2, s = bj & 3;
  const int len = MEAN ? TTS : p.enc_len[b];
  const int sub = lane & 31, grp = lane >> 5;
  float4 q4 = make_float4(0.f, 0.f, 0.f, 0.f);
  if constexpr (!MEAN) q4 = *(const float4*)(qrow + b*DKV + sub*4);
  float m = -1e30f, S = 0.f;
  float4 ca = make_float4(0.f, 0.f, 0.f, 0.f);
  const int t0 = (4*w + s) * 32;   // 64 wave-slots x 32 t cover T=2048
  if (t0 < len) {
    if constexpr (MEAN) {
      const float* vb = p.value + (size_t)b * TTS * DKV;
      for (int tt = 0; tt < 32; tt += 2) {
        int t = t0 + tt + grp;
        float4 v4 = *(const float4*)(vb + (size_t)t*DKV + sub*4);
        S += 1.f;
        ca.x += v4.x; ca.y += v4.y; ca.z += v4.z; ca.w += v4.w;
      }
      m = 0.f;
    } else {
      const int ph = (b*5 + w*3) & 15;
      for (int c4 = 0; c4 < 16; c4 += 4) {   // 4 chunks x 4 row-pairs
        float e[4]; float vx[4][4]; bool val[4];
        #pragma unroll
        for (int j = 0; j < 4; ++j) {
          int jj = (c4 + j + ph) & 15;
          int t = t0 + 2*jj + grp;           // rows exist to T=2048: safe load
          val[j] = t < len;
          float kx, ky, kz, kw;
          if constexpr (BF16) {
            ushort4 ku = *(const ushort4*)(kbf + (size_t)(b*TTS + t)*DKV + sub*4);
            ushort4 vu = *(const ushort4*)(vbf + (size_t)(b*TTS + t)*DKV + sub*4);
            kx = b2f(ku.x); ky = b2f(ku.y); kz = b2f(ku.z); kw = b2f(ku.w);
            vx[j][0] = b2f(vu.x); vx[j][1] = b2f(vu.y);
            vx[j][2] = b2f(vu.z); vx[j][3] = b2f(vu.w);
          } else {
            float4 k4 = *(const float4*)(p.key + (size_t)(b*TTS + t)*DKV + sub*4);
            float4 v4 = *(const float4*)(p.value + (size_t)(b*TTS + t)*DKV + sub*4);
            kx = k4.x; ky = k4.y; kz = k4.z; kw = k4.w;
            vx[j][0] = v4.x; vx[j][1] = v4.y; vx[j][2] = v4.z; vx[j][3] = v4.w;
          }
          float ep = q4.x*kx + q4.y*ky + q4.z*kz + q4.w*kw;
          ep += __shfl_xor(ep, 1); ep += __shfl_xor(ep, 2); ep += __shfl_xor(ep, 4);
          ep += __shfl_xor(ep, 8); ep += __shfl_xor(ep, 16);
          e[j] = val[j] ? ep * SCALE_F : -1e30f;
          if (b == 0 && val[j] && sub == 0) wsE[t] = e[j];
        }
        float mc = fmaxf(fmaxf(e[0], e[1]), fmaxf(e[2], e[3]));
        float mn = fmaxf(m, mc);
        float al = __expf(m - mn);
        float pr[4];
        #pragma unroll
        for (int j = 0; j < 4; ++j) pr[j] = val[j] ? __expf(e[j] - mn) : 0.f;
        S = S*al + pr[0] + pr[1] + pr[2] + pr[3];
        ca.x = ca.x*al + pr[0]*vx[0][0] + pr[1]*vx[1][0] + pr[2]*vx[2][0] + pr[3]*vx[3][0];
        ca.y = ca.y*al + pr[0]*vx[0][1] + pr[1]*vx[1][1] + pr[2]*vx[2][1] + pr[3]*vx[3][1];
        ca.z = ca.z*al + pr[0]*vx[0][2] + pr[1]*vx[1][2] + pr[2]*vx[2][2] + pr[3]*vx[3][2];
        ca.w = ca.w*al + pr[0]*vx[0][3] + pr[1]*vx[1][3] + pr[2]*vx[2][3] + pr[3]*vx[3][3];
        m = mn;
      }
    }
  }
  // merge even/odd half-wave softmax states
  float mo = __shfl_xor(m, 32);
  float M2 = fmaxf(m, mo);
  float as_ = __expf(m - M2), ao = __expf(mo - M2);
  float S2 = S*as_ + __shfl_xor(S, 32)*ao;
  float cx = ca.x*as_ + __shfl_xor(ca.x, 32)*ao;
  float cy = ca.y*as_ + __shfl_xor(ca.y, 32)*ao;
  float cz = ca.z*as_ + __shfl_xor(ca.z, 32)*ao;
  float cw = ca.w*as_ + __shfl_xor(ca.w, 32)*ao;
  if (lane == 0) { sm->c.wm[w] = M2; sm->c.wS[w] = S2; }
  if (grp == 0)
    *(float4*)(sm->c.wctx + w*DKV + sub*4) = make_float4(cx, cy, cz, cw);
  __syncthreads();
  if (tid < DKV) {
    int d = tid;
    float M = -1e30f;
    #pragma unroll
    for (int ww = 0; ww < 16; ++ww) M = fmaxf(M, sm->c.wm[ww]);
    float Z = 0.f, acc2 = 0.f;
    #pragma unroll
    for (int ww = 0; ww < 16; ++ww) {
      float aw = __expf(sm->c.wm[ww] - M);
      Z += aw * sm->c.wS[ww];
      acc2 += aw * sm->c.wctx[ww*DKV + d];
    }
    pctx[d*256 + b*4 + s] = acc2;
    if (d == 0) { pm[b*4 + s] = M; pS[b*4 + s] = Z; }
  }
}

template<bool BF16>
__global__ void __launch_bounds__(NT, 4) decoder_kernel(Params p) {
  const int tid = threadIdx.x;
  const int bj = blockIdx.x;
  float* ws = p.ws;
  unsigned* bar = (unsigned*)(ws + OFF_BAR);
  float* pm = ws + OFF_PM;
  float* pS = ws + OFF_PS;
  float* pctx = ws + OFF_PCTX;
  float* wsE = ws + OFF_WSE;
  float* embT0 = ws + OFF_EMBT;
  float* embT1 = ws + OFF_EMBT + EEM*BB;
  float* h1b0 = ws + OFF_H1;
  float* h1b1 = ws + OFF_H1 + HH1*BB;
  float* c1 = ws + OFF_C1;
  float* h2r0 = ws + OFF_H2R;
  float* h2r1 = ws + OFF_H2R + BB*DKV;
  float* h2t0 = ws + OFF_H2T;
  float* h2t1 = ws + OFF_H2T + DKV*BB;
  float* c2 = ws + OFF_C2;
  unsigned short* kbf = (unsigned short*)(ws + OFF_KBF);
  unsigned short* vbf = (unsigned short*)(ws + OFF_VBF);

  __shared__ SMEM sm;

  // -------- persistent register state: step-invariant weights & biases --------
  float wr1[8] = {0,0,0,0,0,0,0,0};
  if (tid < 896) {
    #pragma unroll
    for (int r = 0; r < 8; ++r) {
      int grow = (r >> 1)*HH1 + 2*bj + (r & 1);
      wr1[r] = (tid < 384) ? p.Wih1[(size_t)grow*384 + tid]
                           : p.Whh1[(size_t)grow*HH1 + (tid - 384)];
    }
  }
  float wr2[8] = {0,0,0,0,0,0,0,0};
  if (bj < 64 && tid < 640) {
    #pragma unroll
    for (int r = 0; r < 8; ++r) {
      int grow = (r >> 1)*DKV + 2*bj + (r & 1);
      wr2[r] = (tid < 512) ? p.Wih2[(size_t)grow*HH1 + tid]
                           : p.Whh2[(size_t)grow*DKV + (tid - 512)];
    }
  }
  float bsum1 = 0.f, bsum2 = 0.f;
  if (tid < 512) {
    int r = tid >> 6;
    int g1 = (r >> 1)*HH1 + 2*bj + (r & 1);
    bsum1 = p.bih1[g1] + p.bhh1[g1];
    if (bj < 64) {
      int g2 = (r >> 1)*DKV + 2*bj + (r & 1);
      bsum2 = p.bih2[g2] + p.bhh2[g2];
    }
  }

  // ---------------- setup ----------------
  {
    int gid = bj*NT + tid;
    for (int idx = gid; idx < (OFF_BAR - OFF_H1); idx += NB*NT) ws[OFF_H1 + idx] = 0.f;
    for (int idx = gid; idx < EEM*BB; idx += NB*NT) {
      int k = idx >> 6, b = idx & 63;
      embT0[k*64 + b] = p.emb[SOS_ID*EEM + k];
    }
    if constexpr (BF16) {
      // convert K,V fp32 -> bf16 (RNE), 8 floats -> one uint4 store
      const int NG = (BB*TTS*DKV) / 8;   // 2097152 groups per tensor
      for (int g = gid; g < NG; g += NB*NT) {
        const float4* src = (const float4*)p.key + (size_t)g*2;
        float4 a = src[0], bq = src[1];
        uint4 o;
        o.x = bfr(a.x)  | (bfr(a.y)  << 16);
        o.y = bfr(a.z)  | (bfr(a.w)  << 16);
        o.z = bfr(bq.x) | (bfr(bq.y) << 16);
        o.w = bfr(bq.z) | (bfr(bq.w) << 16);
        ((uint4*)kbf)[g] = o;
      }
      for (int g = gid; g < NG; g += NB*NT) {
        const float4* src = (const float4*)p.value + (size_t)g*2;
        float4 a = src[0], bq = src[1];
        uint4 o;
        o.x = bfr(a.x)  | (bfr(a.y)  << 16);
        o.y = bfr(a.z)  | (bfr(a.w)  << 16);
        o.z = bfr(bq.x) | (bfr(bq.y) << 16);
        o.w = bfr(bq.z) | (bfr(bq.w) << 16);
        ((uint4*)vbf)[g] = o;
      }
    }
    phase_attn<true, BF16>(p, nullptr, kbf, vbf, pm, pS, pctx, wsE, &sm, bj, tid);
  }
  gbar(bar);

  for (int i = 0; i <= LLS; ++i) {
    const int cur = i & 1;
    float* h1c = cur ? h1b1 : h1b0;
    const float* h1p = cur ? h1b0 : h1b1;
    float* h2rc = cur ? h2r1 : h2r0;
    const float* h2rp = cur ? h2r0 : h2r1;
    float* h2tc = cur ? h2t1 : h2t0;
    const float* h2tp = cur ? h2t0 : h2t1;
    const float* et = cur ? embT1 : embT0;
    float* etn = cur ? embT0 : embT1;

    // ================= phase A =================
    // A0: combine 4 slice partials -> ctx in LDS (transposed [d][b])
    {
      int b = tid & 63, dg = tid >> 6;
      float4 m4 = *(const float4*)(pm + b*4);
      float4 s4 = *(const float4*)(pS + b*4);
      float M = fmaxf(fmaxf(m4.x, m4.y), fmaxf(m4.z, m4.w));
      float a0 = __expf(m4.x - M), a1 = __expf(m4.y - M);
      float a2 = __expf(m4.z - M), a3 = __expf(m4.w - M);
      float Z = a0*s4.x + a1*s4.y + a2*s4.z + a3*s4.w;
      float iZ = 1.f / Z;
      a0 *= iZ; a1 *= iZ; a2 *= iZ; a3 *= iZ;
      #pragma unroll
      for (int jj = 0; jj < 8; ++jj) {
        int d = dg + jj*16;
        float4 c4 = *(const float4*)(pctx + d*256 + b*4);
        sm.a.ctxT[d*64 + b] = a0*c4.x + a1*c4.y + a2*c4.z + a3*c4.w;
      }
    }
    // A1 weights: registers -> LDS (step-invariant, no global traffic)
    if (i < LLS && tid < 896) {
      *(float4*)(sm.a.u.wt + tid*8)     = make_float4(wr1[0], wr1[1], wr1[2], wr1[3]);
      *(float4*)(sm.a.u.wt + tid*8 + 4) = make_float4(wr1[4], wr1[5], wr1[6], wr1[7]);
    }
    __syncthreads();

    if (i < LLS) {
      // A1: LSTM1 for h in {2*bj, 2*bj+1}; 8 gate rows per block
      {
        const int b0 = tid & 15, ks = tid >> 4;   // 16 b-quads x 64 k-slots
        float acc[8][4];
        #pragma unroll
        for (int r = 0; r < 8; ++r) { acc[r][0]=0.f; acc[r][1]=0.f; acc[r][2]=0.f; acc[r][3]=0.f; }
        #pragma unroll
        for (int j = 0; j < 4; ++j) {             // emb segment k<256
          int k = ks*4 + j;
          float4 x4 = *(const float4*)(et + k*64 + b0*4);
          mac8x4(acc, sm.a.u.wt, k, x4);
        }
        #pragma unroll
        for (int j = 0; j < 2; ++j) {             // ctx segment
          int d = ks*2 + j;
          float4 x4 = *(const float4*)(sm.a.ctxT + d*64 + b0*4);
          mac8x4(acc, sm.a.u.wt, 256 + d, x4);
        }
        #pragma unroll
        for (int j = 0; j < 8; ++j) {             // h1 segment
          int kk = ks*8 + j;
          float4 x4 = *(const float4*)(h1p + kk*64 + b0*4);
          mac8x4(acc, sm.a.u.wt, 384 + kk, x4);
        }
        __syncthreads();    // wt reads done; red aliases wt
        gate_reduce_store(acc, sm.a.u.red, tid);
      }
      __syncthreads();
      if (tid < 512) {
        int r = tid >> 6, b = tid & 63;
        float s = 0.f;
        #pragma unroll
        for (int w2 = 0; w2 < 16; ++w2) s += sm.a.u.red[w2*512 + r*64 + b];
        s += bsum1;
        sm.a.u.red[r*64 + b] = s;
      }
      __syncthreads();
      if (tid < 128) {
        int hh = tid >> 6, b = tid & 63;
        int h = 2*bj + hh;
        float gi = sm.a.u.red[(hh+0)*64 + b];
        float gf = sm.a.u.red[(hh+2)*64 + b];
        float gg = sm.a.u.red[(hh+4)*64 + b];
        float go = sm.a.u.red[(hh+6)*64 + b];
        float co = c1[h*64 + b];
        float cn = sigm(gf)*co + sigm(gi)*tanh_f(gg);
        float hn = sigm(go)*tanh_f(cn);
        c1[h*64 + b] = cn;
        h1c[h*64 + b] = hn;
      }
    }

    if (i >= 1) {
      // A2: logits for step i-1
      if (tid >= 960) {
        int ln = tid - 960;
        int oi = bj*8 + (ln >> 3);
        int sub = ln & 7;
        if (oi < BB*VVV) {
          int b = oi / VVV, v = oi - b*VVV;
          float a = 0.f;
          if (sub < 4) {
            #pragma unroll 8
            for (int e0 = 0; e0 < 32; ++e0) {
              int e = sub*32 + e0;
              a += h2rp[b*DKV + e] * p.emb[v*EEM + e];
            }
          } else {
            #pragma unroll 8
            for (int e0 = 0; e0 < 32; ++e0) {
              int d = (sub - 4)*32 + e0;
              a += sm.a.ctxT[d*64 + b] * p.emb[v*EEM + 128 + d];
            }
          }
          a += __shfl_xor(a, 1); a += __shfl_xor(a, 2); a += __shfl_xor(a, 4);
          if (sub == 0) p.out[((size_t)b*LLS + (i-1))*VVV + v] = a + p.obias[v];
        }
      }
      // A3: attention plot row i-1
      if (tid >= 896 && tid < 904) {
        int t = bj*8 + (tid - 896);
        int len0 = p.enc_len[0];
        float v = 0.f;
        if (t < len0) {
          float m0 = pm[0], m1 = pm[1], m2 = pm[2], m3 = pm[3];
          float M = fmaxf(fmaxf(m0, m1), fmaxf(m2, m3));
          float Z = __expf(m0 - M)*pS[0] + __expf(m1 - M)*pS[1]
                  + __expf(m2 - M)*pS[2] + __expf(m3 - M)*pS[3];
          v = __expf(wsE[t] - M) / Z;
        }
        p.out[PRED_SZ + (size_t)(i-1)*TTS + t] = v;
      }
    }

    if (i == LLS) break;
    gbar(bar);

    // ================= phase B =================
    if (bj < 64) {
      if (tid < 640) {
        *(float4*)(sm.a.u.wt + tid*8)     = make_float4(wr2[0], wr2[1], wr2[2], wr2[3]);
        *(float4*)(sm.a.u.wt + tid*8 + 4) = make_float4(wr2[4], wr2[5], wr2[6], wr2[7]);
      }
      __syncthreads();
      {
        const int b0 = tid & 15, ks = tid >> 4;
        float acc[8][4];
        #pragma unroll
        for (int r = 0; r < 8; ++r) { acc[r][0]=0.f; acc[r][1]=0.f; acc[r][2]=0.f; acc[r][3]=0.f; }
        #pragma unroll
        for (int j = 0; j < 8; ++j) {            // h1 segment (512)
          int k = ks*8 + j;
          float4 x4 = *(const float4*)(h1c + k*64 + b0*4);
          mac8x4(acc, sm.a.u.wt, k, x4);
        }
        #pragma unroll
        for (int j = 0; j < 2; ++j) {            // h2 segment (128)
          int d = ks*2 + j;
          float4 x4 = *(const float4*)(h2tp + d*64 + b0*4);
          mac8x4(acc, sm.a.u.wt, 512 + d, x4);
        }
        __syncthreads();
        gate_reduce_store(acc, sm.a.u.red, tid);
      }
      __syncthreads();
      if (tid < 512) {
        int r = tid >> 6, b = tid & 63;
        float s = 0.f;
        #pragma unroll
        for (int w2 = 0; w2 < 16; ++w2) s += sm.a.u.red[w2*512 + r*64 + b];
        s += bsum2;
        sm.a.u.red[r*64 + b] = s;
      }
      __syncthreads();
      if (tid < 128) {
        int hh = tid >> 6, b = tid & 63;
        int d2 = 2*bj + hh;
        float gi = sm.a.u.red[(hh+0)*64 + b];
        float gf = sm.a.u.red[(hh+2)*64 + b];
        float gg = sm.a.u.red[(hh+4)*64 + b];
        float go = sm.a.u.red[(hh+6)*64 + b];
        float co = c2[d2*64 + b];
        float cn = sigm(gf)*co + sigm(gi)*tanh_f(gg);
        float hn = sigm(go)*tanh_f(cn);
        c2[d2*64 + b] = cn;
        h2rc[b*DKV + d2] = hn;
        h2tc[d2*64 + b] = hn;
      }
    } else if (bj < 128) {
      // stage embeddings for step i+1
      int sn = i + 1;
      if (sn < LLS && tid < 256) {
        int idx = (bj - 64)*256 + tid;
        int k = idx >> 6, b = idx & 63;
        int id = p.y[b*LLS + sn - 1];
        etn[k*64 + b] = p.emb[(size_t)id*EEM + k];
      }
    }
    gbar(bar);

    // ================= phase C =================
    phase_attn<false, BF16>(p, h2rc, kbf, vbf, pm, pS, pctx, wsE, &sm, bj, tid);
    gbar(bar);
  }
}

__global__ void init_bar_kernel(unsigned* bar) {
  int i = blockIdx.x * blockDim.x + threadIdx.x;
  if (i < 2048) bar[i] = 0u;
}

extern "C" void kernel_launch(void* const* d_in, const int* in_sizes, int n_in,
                              void* d_out, int out_size, void* d_ws, size_t ws_size,
                              hipStream_t stream) {
  Params prm;
  prm.key     = (const float*)d_in[0];
  prm.value   = (const float*)d_in[1];
  prm.enc_len = (const int*)d_in[2];
  prm.y       = (const int*)d_in[3];
  prm.emb     = (const float*)d_in[4];
  prm.Wih1    = (const float*)d_in[5];
  prm.Whh1    = (const float*)d_in[6];
  prm.bih1    = (const float*)d_in[7];
  prm.bhh1    = (const float*)d_in[8];
  prm.Wih2    = (const float*)d_in[9];
  prm.Whh2    = (const float*)d_in[10];
  prm.bih2    = (const float*)d_in[11];
  prm.bhh2    = (const float*)d_in[12];
  prm.obias   = (const float*)d_in[13];
  prm.out = (float*)d_out;
  prm.ws  = (float*)d_ws;

  unsigned* bar = (unsigned*)((float*)d_ws + OFF_BAR);
  init_bar_kernel<<<8, 256, 0, stream>>>(bar);

  void* args[] = { &prm };
  if (ws_size >= WS_NEED_BYTES) {
    hipError_t e = hipLaunchCooperativeKernel((const void*)decoder_kernel<true>,
                                              dim3(NB), dim3(NT), args, 0, stream);
    if (e != hipSuccess) decoder_kernel<true><<<dim3(NB), dim3(NT), 0, stream>>>(prm);
  } else {
    hipError_t e = hipLaunchCooperativeKernel((const void*)decoder_kernel<false>,
                                              dim3(NB), dim3(NT), args, 0, stream);
    if (e != hipSuccess) decoder_kernel<false><<<dim3(NB), dim3(NT), 0, stream>>>(prm);
  }
}